// Round 8
// baseline (1161.216 us; speedup 1.0000x reference)
//
#include <hip/hip_runtime.h>
#include <hip/hip_bf16.h>

#define HID 50
#define FOURH 200
#define TSTEPS 2048
#define NBATCH 1024

typedef _Float16 v2h __attribute__((ext_vector_type(2)));

#define LOG2E 1.44269504f

__device__ __forceinline__ float frcp(float x)  { return __builtin_amdgcn_rcpf(x); }
__device__ __forceinline__ float fexp2(float x) { return __builtin_amdgcn_exp2f(x); }

__device__ __forceinline__ float fast_sigmoid(float x) {
    return frcp(1.0f + fexp2(-LOG2E * x));   // NaN-free both tails
}
__device__ __forceinline__ float fast_tanh(float x) {
    return 1.0f - 2.0f * frcp(fexp2((2.0f * LOG2E) * x) + 1.0f);  // saturating
}
__device__ __forceinline__ v2h bc_v2h(unsigned int u) {
    return __builtin_bit_cast(v2h, u);
}
// Opaque VGPR launder: compiler can no longer rematerialize/reload the value.
// (R7's failure: VGPR_Count=32 -> Wh reloaded from L2 every step, ~42TB.)
__device__ __forceinline__ unsigned int pin_u32(unsigned int v) {
    asm volatile("" : "+v"(v));
    return v;
}
__device__ __forceinline__ float pin_f32(float v) {
    asm volatile("" : "+v"(v));
    return v;
}

// One block (256 thr, 4 waves) per batch; 1024 blocks -> 4 blocks/CU (TLP
// across independent batches). Thread tid<200 owns gate column tid: 25
// v_dot2_f32_f16/step, Wh column PINNED in VGPRs (half2-packed). h broadcast
// via LDS f16 (7x ds_read_b128). Gate phase (transcendentals + c/h update)
// runs on wave (b + b>>8)&3 so co-resident blocks put their act chains on
// DIFFERENT SIMDs (all-wave0 would pile ~440 transc-cycles on SIMD0).
__global__ __launch_bounds__(256, 4)
void lstm_col2_kernel(const float* __restrict__ x,
                      const float* __restrict__ Wx,
                      const float* __restrict__ Wh,
                      const float* __restrict__ bias,
                      const float* __restrict__ Wd,
                      const float* __restrict__ bd,
                      float* __restrict__ out) {
    const int b    = blockIdx.x;
    const int tid  = threadIdx.x;
    const int wv   = tid >> 6;
    const int lane = tid & 63;
    const bool is_col = (tid < FOURH);
    const int col = is_col ? tid : (FOURH - 1);
    const int u = col % HID;                  // unit of this column
    const int g = col / HID;                  // gate of this column
    const int act_wave = (b + (b >> 8)) & 3;  // balanced under either placement
    const bool is_act = (wv == act_wave) && (lane < HID);

    __shared__ __align__(16) float    xs[TSTEPS + 4];
    __shared__ __align__(16) _Float16 hbuf[56];    // h (f16), [50..55] zero pad
    __shared__ __align__(16) float    zbuf[4][52]; // z per gate, padded rows

    // Stage x (coalesced float4).
    const float4* xb4 = (const float4*)(x + (size_t)b * TSTEPS);
    float4* xs4 = (float4*)xs;
    #pragma unroll
    for (int i = tid; i < TSTEPS / 4; i += 256) xs4[i] = xb4[i];
    if (tid == 0) xs[TSTEPS] = 0.0f;
    if (tid < 56) hbuf[tid] = (_Float16)0.0f;

    // Column weights: Wh[:,col] packed half2 along k, PINNED in VGPRs.
    v2h w[25];
    #pragma unroll
    for (int k2 = 0; k2 < 25; ++k2) {
        v2h t = v2h{(_Float16)Wh[(2 * k2) * FOURH + col],
                    (_Float16)Wh[(2 * k2 + 1) * FOURH + col]};
        w[k2] = bc_v2h(pin_u32(__builtin_bit_cast(unsigned int, t)));
    }
    const float wx_c = pin_f32(Wx[col]);
    const float b_c  = pin_f32(bias[col]);

    float c = 0.0f;
    float h = 0.0f;   // act-wave lanes' register copy of h_lane
    __syncthreads();

    const uint4* hb4 = (const uint4*)hbuf;   // 7 x b128 = 56 halves

    for (int t = 0; t < TSTEPS; ++t) {
        // ---- dot phase (all threads compute; only columns write) ----
        {
            const float xt = xs[t];
            const uint4 q0 = hb4[0], q1 = hb4[1], q2 = hb4[2], q3 = hb4[3];
            const uint4 q4 = hb4[4], q5 = hb4[5], q6 = hb4[6];
            float a0 = 0.f, a1 = 0.f, a2 = 0.f, a3 = 0.f;
            a0 = __builtin_amdgcn_fdot2(w[0],  bc_v2h(q0.x), a0, false);
            a1 = __builtin_amdgcn_fdot2(w[1],  bc_v2h(q0.y), a1, false);
            a2 = __builtin_amdgcn_fdot2(w[2],  bc_v2h(q0.z), a2, false);
            a3 = __builtin_amdgcn_fdot2(w[3],  bc_v2h(q0.w), a3, false);
            a0 = __builtin_amdgcn_fdot2(w[4],  bc_v2h(q1.x), a0, false);
            a1 = __builtin_amdgcn_fdot2(w[5],  bc_v2h(q1.y), a1, false);
            a2 = __builtin_amdgcn_fdot2(w[6],  bc_v2h(q1.z), a2, false);
            a3 = __builtin_amdgcn_fdot2(w[7],  bc_v2h(q1.w), a3, false);
            a0 = __builtin_amdgcn_fdot2(w[8],  bc_v2h(q2.x), a0, false);
            a1 = __builtin_amdgcn_fdot2(w[9],  bc_v2h(q2.y), a1, false);
            a2 = __builtin_amdgcn_fdot2(w[10], bc_v2h(q2.z), a2, false);
            a3 = __builtin_amdgcn_fdot2(w[11], bc_v2h(q2.w), a3, false);
            a0 = __builtin_amdgcn_fdot2(w[12], bc_v2h(q3.x), a0, false);
            a1 = __builtin_amdgcn_fdot2(w[13], bc_v2h(q3.y), a1, false);
            a2 = __builtin_amdgcn_fdot2(w[14], bc_v2h(q3.z), a2, false);
            a3 = __builtin_amdgcn_fdot2(w[15], bc_v2h(q3.w), a3, false);
            a0 = __builtin_amdgcn_fdot2(w[16], bc_v2h(q4.x), a0, false);
            a1 = __builtin_amdgcn_fdot2(w[17], bc_v2h(q4.y), a1, false);
            a2 = __builtin_amdgcn_fdot2(w[18], bc_v2h(q4.z), a2, false);
            a3 = __builtin_amdgcn_fdot2(w[19], bc_v2h(q4.w), a3, false);
            a0 = __builtin_amdgcn_fdot2(w[20], bc_v2h(q5.x), a0, false);
            a1 = __builtin_amdgcn_fdot2(w[21], bc_v2h(q5.y), a1, false);
            a2 = __builtin_amdgcn_fdot2(w[22], bc_v2h(q5.z), a2, false);
            a3 = __builtin_amdgcn_fdot2(w[23], bc_v2h(q5.w), a3, false);
            a0 = __builtin_amdgcn_fdot2(w[24], bc_v2h(q6.x), a0, false);
            const float z = fmaf(xt, wx_c, b_c) + (a0 + a1) + (a2 + a3);
            if (is_col) zbuf[g][u] = z;
        }
        __syncthreads();
        // ---- gate phase: one wave per block, rotated across SIMDs ----
        if (is_act) {
            const float zi = zbuf[0][lane];
            const float zf = zbuf[1][lane];
            const float zg = zbuf[2][lane];
            const float zo = zbuf[3][lane];
            const float ig = fast_sigmoid(zi);
            const float fg = fast_sigmoid(zf);
            const float gg = fast_tanh(zg);
            const float og = fast_sigmoid(zo);
            c = fmaf(fg, c, ig * gg);
            h = og * fast_tanh(c);
            hbuf[lane] = (_Float16)h;
        }
        __syncthreads();
    }

    // out[b] = h_T . Wd + bd (act wave holds fp32 h; reduce within it)
    if (wv == act_wave) {
        float v = (lane < HID) ? h * Wd[lane] : 0.0f;
        #pragma unroll
        for (int off = 32; off > 0; off >>= 1) v += __shfl_down(v, off);
        if (lane == 0) out[b] = v + bd[0];
    }
}

extern "C" void kernel_launch(void* const* d_in, const int* in_sizes, int n_in,
                              void* d_out, int out_size, void* d_ws, size_t ws_size,
                              hipStream_t stream) {
    const float* x    = (const float*)d_in[0];  // [1024, 2048, 1]
    const float* Wx   = (const float*)d_in[1];  // [1, 200]
    const float* Wh   = (const float*)d_in[2];  // [50, 200]
    const float* bias = (const float*)d_in[3];  // [200]
    const float* Wd   = (const float*)d_in[4];  // [50, 1]
    const float* bd   = (const float*)d_in[5];  // [1]
    float* out = (float*)d_out;                 // [1024, 1]

    lstm_col2_kernel<<<dim3(NBATCH), dim3(256), 0, stream>>>(
        x, Wx, Wh, bias, Wd, bd, out);
}

// Round 9
// 995.103 us; speedup vs baseline: 1.1669x; 1.1669x over previous
//
#include <hip/hip_runtime.h>
#include <hip/hip_bf16.h>

#define HID 50
#define FOURH 200
#define TSTEPS 2048
#define NBATCH 1024
#define BPB 2              // real batches per block (MFMA M=16, rows >=BPB zero)
#define NT 13              // N tiles of 16 cols (200 -> 208 padded)

typedef _Float16 half8 __attribute__((ext_vector_type(8)));
typedef float    f32x4 __attribute__((ext_vector_type(4)));

#define LOG2E 1.44269504f

__device__ __forceinline__ float frcp(float x)  { return __builtin_amdgcn_rcpf(x); }
__device__ __forceinline__ float fexp2(float x) { return __builtin_amdgcn_exp2f(x); }
__device__ __forceinline__ float fast_sigmoid(float x) {
    return frcp(1.0f + fexp2(-LOG2E * x));                      // NaN-free tails
}
__device__ __forceinline__ float fast_tanh(float x) {
    return 1.0f - 2.0f * frcp(fexp2((2.0f * LOG2E) * x) + 1.0f); // saturating
}

// MFMA LSTM: block = 256 thr (4 waves) owns BPB=2 batches for all T steps.
// Recurrent GEMV Z[16,200] = H[16,50(pad64)] @ Wh -> 16x16x32_f16 MFMA pairs:
// wave w owns N-tiles {w, w+4, w+8, (12 if w==0)}, B-frags resident in VGPRs.
// A (= h, f16) read from LDS h16[16][72] as 2x ds_read_b128 per lane.
// Z lands in C-layout (col=lane&15=n, row=(lane>>4)*4+reg=m) -> b128 store to
// zsh[n][m..] -> act threads (t<100: u=t%50, b=t/50) read 4 gate scalars, do
// fp32 x-path/bias/activations (R6 numerics), write h back as f16.
// 512 blocks -> 2 blocks/CU co-resident: the other block hides barriers.
__global__ __launch_bounds__(256, 2)
void lstm_mfma_kernel(const float* __restrict__ x,
                      const float* __restrict__ Wx,
                      const float* __restrict__ Wh,
                      const float* __restrict__ bias,
                      const float* __restrict__ Wd,
                      const float* __restrict__ bd,
                      float* __restrict__ out) {
    const int tid  = threadIdx.x;
    const int w    = tid >> 6;        // wave 0..3
    const int lane = tid & 63;
    const int ln16 = lane & 15;       // n (B/D col) and m (A row) index
    const int q    = lane >> 4;       // quad 0..3
    const int bglob0 = blockIdx.x * BPB;

    __shared__ __align__(16) _Float16 h16[16][72];   // h state, f16, k-padded
    __shared__ __align__(16) float    zsh[208][20];  // Z: [col][m-row(+pad)]
    __shared__ __align__(16) float    xs[TSTEPS][BPB];

    // ---- stage x: wave b stages batch b (coalesced float4) ----
    if (w < BPB) {
        const float4* xg4 = (const float4*)(x + (size_t)(bglob0 + w) * TSTEPS);
        #pragma unroll
        for (int n = 0; n < TSTEPS / (4 * 64); ++n) {
            const float4 v = xg4[n * 64 + lane];
            const int t0 = (n * 64 + lane) * 4;
            xs[t0 + 0][w] = v.x; xs[t0 + 1][w] = v.y;
            xs[t0 + 2][w] = v.z; xs[t0 + 3][w] = v.w;
        }
    }
    // zero h state (rows >= BPB and k >= 50 stay zero forever)
    for (int i = tid; i < 16 * 72; i += 256) ((_Float16*)h16)[i] = (_Float16)0.0f;

    // ---- B-fragments: Wh[k][n], lane holds k = q*8+j (+32 for ktile1) ----
    half8 bf0[4], bf1[4];
    #pragma unroll
    for (int idx = 0; idx < 4; ++idx) {
        half8 b0, b1;
        #pragma unroll
        for (int j = 0; j < 8; ++j) { b0[j] = (_Float16)0.0f; b1[j] = (_Float16)0.0f; }
        const int tile = w + 4 * idx;
        if (tile < NT) {
            const int n = tile * 16 + ln16;
            if (n < FOURH) {
                #pragma unroll
                for (int j = 0; j < 8; ++j) {
                    const int k0 = q * 8 + j;          // 0..31, always < HID
                    const int k1 = k0 + 32;            // 32..63
                    b0[j] = (_Float16)Wh[k0 * FOURH + n];
                    b1[j] = (k1 < HID) ? (_Float16)Wh[k1 * FOURH + n] : (_Float16)0.0f;
                }
            }
        }
        bf0[idx] = b0; bf1[idx] = b1;
    }

    // ---- act-thread constants (threads 0..BPB*HID-1) ----
    const bool is_act = (tid < BPB * HID);
    const int  uc = is_act ? (tid % HID) : 0;   // unit
    const int  bc = is_act ? (tid / HID) : 0;   // batch row
    const float wx_i = Wx[uc],            b_i = bias[uc];
    const float wx_f = Wx[HID + uc],      b_f = bias[HID + uc];
    const float wx_g = Wx[2 * HID + uc],  b_g = bias[2 * HID + uc];
    const float wx_o = Wx[3 * HID + uc],  b_o = bias[3 * HID + uc];

    float c = 0.0f, hreg = 0.0f;
    __syncthreads();

    for (int t = 0; t < TSTEPS; ++t) {
        // ---- A-frags from h16: lane m=ln16, k = q*8+j (+32) ----
        const uint4* hrow = (const uint4*)&h16[ln16][0];   // 144 B = 9 uint4
        const half8 a0 = __builtin_bit_cast(half8, hrow[q]);       // k 0..31
        const half8 a1 = __builtin_bit_cast(half8, hrow[q + 4]);   // k 32..63

        // ---- MFMA + Z store (wave-uniform tile guard) ----
        #pragma unroll
        for (int idx = 0; idx < 4; ++idx) {
            const int tile = w + 4 * idx;
            if (tile < NT) {
                f32x4 acc = {0.0f, 0.0f, 0.0f, 0.0f};
                acc = __builtin_amdgcn_mfma_f32_16x16x32_f16(a0, bf0[idx], acc, 0, 0, 0);
                acc = __builtin_amdgcn_mfma_f32_16x16x32_f16(a1, bf1[idx], acc, 0, 0, 0);
                // D[m][n]: col n = ln16, rows m = q*4+r  -> zsh[n][q*4..q*4+3]
                *(f32x4*)&zsh[tile * 16 + ln16][q * 4] = acc;
            }
        }
        __syncthreads();

        // ---- act phase: 100 threads, 1 (unit,batch) each, fp32 ----
        if (is_act) {
            const float xt = xs[t][bc];
            const float zi = fmaf(xt, wx_i, zsh[uc][bc]             + b_i);
            const float zf = fmaf(xt, wx_f, zsh[HID + uc][bc]       + b_f);
            const float zg = fmaf(xt, wx_g, zsh[2 * HID + uc][bc]   + b_g);
            const float zo = fmaf(xt, wx_o, zsh[3 * HID + uc][bc]   + b_o);
            const float ig = fast_sigmoid(zi);
            const float fg = fast_sigmoid(zf);
            const float gg = fast_tanh(zg);
            const float og = fast_sigmoid(zo);
            c = fmaf(fg, c, ig * gg);
            hreg = og * fast_tanh(c);
            h16[bc][uc] = (_Float16)hreg;
        }
        __syncthreads();
    }

    // ---- output: out[b] = h . Wd + bd ----
    if (is_act) zsh[uc][bc] = hreg * Wd[uc];
    __syncthreads();
    if (tid < BPB) {
        float s = 0.0f;
        for (int u = 0; u < HID; ++u) s += zsh[u][tid];
        out[bglob0 + tid] = s + bd[0];
    }
}

extern "C" void kernel_launch(void* const* d_in, const int* in_sizes, int n_in,
                              void* d_out, int out_size, void* d_ws, size_t ws_size,
                              hipStream_t stream) {
    const float* x    = (const float*)d_in[0];  // [1024, 2048, 1]
    const float* Wx   = (const float*)d_in[1];  // [1, 200]
    const float* Wh   = (const float*)d_in[2];  // [50, 200]
    const float* bias = (const float*)d_in[3];  // [200]
    const float* Wd   = (const float*)d_in[4];  // [50, 1]
    const float* bd   = (const float*)d_in[5];  // [1]
    float* out = (float*)d_out;                 // [1024, 1]

    lstm_mfma_kernel<<<dim3(NBATCH / BPB), dim3(256), 0, stream>>>(
        x, Wx, Wh, bias, Wd, bd, out);
}

// Round 10
// 967.495 us; speedup vs baseline: 1.2002x; 1.0285x over previous
//
#include <hip/hip_runtime.h>
#include <hip/hip_bf16.h>

#define HID 50
#define FOURH 200
#define TSTEPS 2048
#define NBATCH 1024
#define BPB 2              // real batches per block (MFMA rows >= BPB are zero)
#define NT 13              // 13 N-tiles x 16 = 208 >= 200
#define XROW 2056          // xs row stride in floats (16B aligned, +pad slot)

typedef _Float16 half8 __attribute__((ext_vector_type(8)));
typedef float    f32x4 __attribute__((ext_vector_type(4)));
typedef float    f32x2 __attribute__((ext_vector_type(2)));

#define LOG2E 1.44269504f

__device__ __forceinline__ float frcp(float x)  { return __builtin_amdgcn_rcpf(x); }
__device__ __forceinline__ float fexp2(float x) { return __builtin_amdgcn_exp2f(x); }
__device__ __forceinline__ float fast_sigmoid(float x) {
    return frcp(1.0f + fexp2(-LOG2E * x));                       // NaN-free tails
}
__device__ __forceinline__ float fast_tanh(float x) {
    return 1.0f - 2.0f * frcp(fexp2((2.0f * LOG2E) * x) + 1.0f); // saturating
}

// MFMA LSTM v2 (latency-trimmed R9). Block = 256 thr / 4 waves owns 2 batches.
// Z[16,208] = Hext[16,64] @ Whext via 16x16x32_f16 pairs; K slots 50/51 carry
// x_t and 1.0 so Wx and bias ride the MFMA (act phase is pure nonlinearity).
// Z lives only in q==0 lanes (rows 0,1 = acc[0],acc[1]) -> one conflict-free
// ds_write_b64 per tile into zsh[208][2]. Act: 100 threads (u,b), 4 scalar z
// reads, R6 numerics, write h (+x_{t+1} prefetch) back to h16 as f16.
// 512 blocks -> 2/CU. Layouts identical to R9 (HW-verified, absmax 1.2e-4).
__global__ __launch_bounds__(256, 2)
void lstm_mfma2_kernel(const float* __restrict__ x,
                       const float* __restrict__ Wx,
                       const float* __restrict__ Wh,
                       const float* __restrict__ bias,
                       const float* __restrict__ Wd,
                       const float* __restrict__ bd,
                       float* __restrict__ out) {
    const int tid  = threadIdx.x;
    const int w    = tid >> 6;
    const int lane = tid & 63;
    const int ln16 = lane & 15;       // m (A row) / n (B,D col) index
    const int q    = lane >> 4;       // quad 0..3
    const int bg0  = blockIdx.x * BPB;

    __shared__ __align__(16) _Float16 h16[16][72];   // Hext: h | x | 1 | pad
    __shared__ __align__(16) float    zsh[208][2];   // Z rows 0,1 only
    __shared__ __align__(16) float    xs[BPB][XROW];

    // ---- stage x: wave b stages batch b (coalesced float4) ----
    if (w < BPB) {
        const float4* xg4 = (const float4*)(x + (size_t)(bg0 + w) * TSTEPS);
        float4* xr4 = (float4*)&xs[w][0];
        #pragma unroll
        for (int i = 0; i < TSTEPS / (4 * 64); ++i)
            xr4[i * 64 + lane] = xg4[i * 64 + lane];
        if (lane == 0) { xs[w][TSTEPS] = 0.0f; }     // t+1 pad
    }
    for (int i = tid; i < 16 * 72; i += 256) ((_Float16*)h16)[i] = (_Float16)0.0f;
    __syncthreads();
    if (tid < BPB) {                  // x_0 and bias-row constant
        h16[tid][50] = (_Float16)xs[tid][0];
        h16[tid][51] = (_Float16)1.0f;
    }

    // ---- B-fragments: Whext[k][n]; k=50 -> Wx, k=51 -> bias ----
    half8 bf0[4], bf1[4];
    #pragma unroll
    for (int idx = 0; idx < 4; ++idx) {
        half8 b0, b1;
        #pragma unroll
        for (int j = 0; j < 8; ++j) { b0[j] = (_Float16)0.0f; b1[j] = (_Float16)0.0f; }
        const int tile = w + 4 * idx;
        if (tile < NT) {
            const int n = tile * 16 + ln16;
            if (n < FOURH) {
                #pragma unroll
                for (int j = 0; j < 8; ++j) {
                    const int k0 = q * 8 + j;          // 0..31 (< HID)
                    const int k1 = k0 + 32;            // 32..63
                    b0[j] = (_Float16)Wh[k0 * FOURH + n];
                    float v1 = 0.0f;
                    if (k1 < HID)       v1 = Wh[k1 * FOURH + n];
                    else if (k1 == 50)  v1 = Wx[n];
                    else if (k1 == 51)  v1 = bias[n];
                    b1[j] = (_Float16)v1;
                }
            }
        }
        bf0[idx] = b0; bf1[idx] = b1;
    }

    // ---- act-thread mapping: tid<100 -> (unit uc, batch bc) ----
    const bool is_act = (tid < BPB * HID);
    const int  uc = (tid < HID) ? tid : (tid - HID);
    const int  bc = (tid < HID) ? 0 : 1;

    float c = 0.0f, hreg = 0.0f;
    __syncthreads();

    for (int t = 0; t < TSTEPS; ++t) {
        // ---- A-frags: lane (m=ln16), k = q*8+j (a0), +32 (a1) ----
        const uint4* hrow = (const uint4*)&h16[ln16][0];
        const half8 a0 = __builtin_bit_cast(half8, hrow[q]);
        const half8 a1 = __builtin_bit_cast(half8, hrow[q + 4]);

        // ---- MFMA per tile; q==0 lanes store rows 0,1 as one b64 ----
        #pragma unroll
        for (int idx = 0; idx < 4; ++idx) {
            const int tile = w + 4 * idx;
            if (tile < NT) {
                f32x4 acc = {0.0f, 0.0f, 0.0f, 0.0f};
                acc = __builtin_amdgcn_mfma_f32_16x16x32_f16(a0, bf0[idx], acc, 0, 0, 0);
                acc = __builtin_amdgcn_mfma_f32_16x16x32_f16(a1, bf1[idx], acc, 0, 0, 0);
                if (q == 0) {
                    f32x2 zr = {acc[0], acc[1]};     // rows 0,1 of col
                    *(f32x2*)&zsh[tile * 16 + ln16][0] = zr;
                }
            }
        }
        __syncthreads();

        // ---- act: 100 threads, z is the full preactivation already ----
        if (is_act) {
            const float zi = zsh[uc][bc];
            const float zf = zsh[HID + uc][bc];
            const float zg = zsh[2 * HID + uc][bc];
            const float zo = zsh[3 * HID + uc][bc];
            const float ig = fast_sigmoid(zi);
            const float fg = fast_sigmoid(zf);
            const float gg = fast_tanh(zg);
            const float og = fast_sigmoid(zo);
            c = fmaf(fg, c, ig * gg);
            hreg = og * fast_tanh(c);
            h16[bc][uc] = (_Float16)hreg;
            if (uc == 0) h16[bc][50] = (_Float16)xs[bc][t + 1];  // next x
        }
        __syncthreads();
    }

    // ---- output: out[b] = h . Wd + bd ----
    if (is_act) zsh[uc][bc] = hreg * Wd[uc];
    __syncthreads();
    if (tid < BPB) {
        float s = 0.0f;
        for (int u = 0; u < HID; ++u) s += zsh[u][tid];
        out[bg0 + tid] = s + bd[0];
    }
}

extern "C" void kernel_launch(void* const* d_in, const int* in_sizes, int n_in,
                              void* d_out, int out_size, void* d_ws, size_t ws_size,
                              hipStream_t stream) {
    const float* x    = (const float*)d_in[0];  // [1024, 2048, 1]
    const float* Wx   = (const float*)d_in[1];  // [1, 200]
    const float* Wh   = (const float*)d_in[2];  // [50, 200]
    const float* bias = (const float*)d_in[3];  // [200]
    const float* Wd   = (const float*)d_in[4];  // [50, 1]
    const float* bd   = (const float*)d_in[5];  // [1]
    float* out = (float*)d_out;                 // [1024, 1]

    lstm_mfma2_kernel<<<dim3(NBATCH / BPB), dim3(256), 0, stream>>>(
        x, Wx, Wh, bias, Wd, bd, out);
}